// Round 1
// baseline (171.436 us; speedup 1.0000x reference)
//
#include <hip/hip_runtime.h>
#include <math.h>

#define DD 4096
#define EE 64
#define NEG_SENTINEL -1.0e30f

// ---------------------------------------------------------------------------
// Kernel 1: partial GEMM  logits[n][e] = sum_k hidden[n][k] * gate_w[e][k]
// grid.x = row blocks (64 rows), grid.y = KSPLIT (K-slices)
// block = 256 threads, thread tile 4 rows x 4 experts
// LDS tiles stored transposed [k][row] (pitch 68 -> 16B aligned, ~2-way banks)
// ---------------------------------------------------------------------------
template <int KSPLIT>
__global__ __launch_bounds__(256, 4) void gemm_partial(
    const float* __restrict__ hidden, const float* __restrict__ gate_w,
    float* __restrict__ part, int nrows) {
  __shared__ float As[64][68];
  __shared__ float Bs[64][68];

  const int tid = threadIdx.x;
  const int tx = tid & 15;   // m-group (16)
  const int ty = tid >> 4;   // e-group (16)
  const int tx4 = tx * 4;
  const int ty4 = ty * 4;
  const int m0 = blockIdx.x * 64;
  const int kslice = DD / KSPLIT;
  const int k0 = blockIdx.y * kslice;

  float acc[4][4] = {};

  for (int kt = 0; kt < kslice; kt += 64) {
    const int kb = k0 + kt;
    // Stage A (64 rows x 64 k) and B (64 experts x 64 k), transposed to [k][r]
#pragma unroll
    for (int i = 0; i < 4; i++) {
      const int r = ty + 16 * i;  // row / expert index 0..63
      float4 va = *(const float4*)&hidden[(size_t)(m0 + r) * DD + kb + tx4];
      As[tx4 + 0][r] = va.x;
      As[tx4 + 1][r] = va.y;
      As[tx4 + 2][r] = va.z;
      As[tx4 + 3][r] = va.w;
      float4 vb = *(const float4*)&gate_w[(size_t)r * DD + kb + tx4];
      Bs[tx4 + 0][r] = vb.x;
      Bs[tx4 + 1][r] = vb.y;
      Bs[tx4 + 2][r] = vb.z;
      Bs[tx4 + 3][r] = vb.w;
    }
    __syncthreads();
#pragma unroll 8
    for (int kk = 0; kk < 64; kk++) {
      float4 a = *(const float4*)&As[kk][tx4];
      float4 b = *(const float4*)&Bs[kk][ty4];
      acc[0][0] = fmaf(a.x, b.x, acc[0][0]);
      acc[0][1] = fmaf(a.x, b.y, acc[0][1]);
      acc[0][2] = fmaf(a.x, b.z, acc[0][2]);
      acc[0][3] = fmaf(a.x, b.w, acc[0][3]);
      acc[1][0] = fmaf(a.y, b.x, acc[1][0]);
      acc[1][1] = fmaf(a.y, b.y, acc[1][1]);
      acc[1][2] = fmaf(a.y, b.z, acc[1][2]);
      acc[1][3] = fmaf(a.y, b.w, acc[1][3]);
      acc[2][0] = fmaf(a.z, b.x, acc[2][0]);
      acc[2][1] = fmaf(a.z, b.y, acc[2][1]);
      acc[2][2] = fmaf(a.z, b.z, acc[2][2]);
      acc[2][3] = fmaf(a.z, b.w, acc[2][3]);
      acc[3][0] = fmaf(a.w, b.x, acc[3][0]);
      acc[3][1] = fmaf(a.w, b.y, acc[3][1]);
      acc[3][2] = fmaf(a.w, b.z, acc[3][2]);
      acc[3][3] = fmaf(a.w, b.w, acc[3][3]);
    }
    __syncthreads();
  }

  // Write partial logits: part[ks][row][e]
  float* dst = part + (size_t)blockIdx.y * nrows * EE;
#pragma unroll
  for (int i = 0; i < 4; i++) {
    float4 v = make_float4(acc[i][0], acc[i][1], acc[i][2], acc[i][3]);
    *(float4*)&dst[(size_t)(m0 + tx4 + i) * EE + ty4] = v;
  }
}

// ---------------------------------------------------------------------------
// Kernel 2: reduce K-split partials, sqrt(softplus), top-8 (lower-index
// tie-break like lax.top_k), renormalize, scatter probs + routing map.
// One wave (64 lanes) per row; lane == expert.
// ---------------------------------------------------------------------------
__global__ __launch_bounds__(256) void topk_kernel(
    const float* __restrict__ part, const float* __restrict__ bias,
    float* __restrict__ out, int nrows, int ksplit) {
  const int lane = threadIdx.x & 63;
  const int row = blockIdx.x * 4 + (threadIdx.x >> 6);

  float logit = 0.0f;
  for (int s = 0; s < ksplit; s++)
    logit += part[(size_t)s * nrows * EE + (size_t)row * EE + lane];

  // softplus, numerically stable
  float sp = (logit > 0.0f) ? (logit + log1pf(expf(-logit)))
                            : log1pf(expf(logit));
  float score = sqrtf(sp);
  float sel = score + bias[lane];

  float denom = 0.0f;
  bool chosen = false;
#pragma unroll
  for (int t = 0; t < 8; t++) {
    float v = sel;
    int idx = lane;
#pragma unroll
    for (int m = 1; m < 64; m <<= 1) {
      float ov = __shfl_xor(v, m, 64);
      int oi = __shfl_xor(idx, m, 64);
      if (ov > v || (ov == v && oi < idx)) {
        v = ov;
        idx = oi;
      }
    }
    // idx = argmax across wave (uniform)
    float wscore = __shfl(score, idx, 64);
    denom += wscore;
    if (lane == idx) {
      chosen = true;
      sel = NEG_SENTINEL;
    }
  }
  denom = fmaxf(denom, 1e-12f);

  out[(size_t)row * EE + lane] = chosen ? (score / denom) : 0.0f;
  out[(size_t)nrows * EE + (size_t)row * EE + lane] = chosen ? 1.0f : 0.0f;
}

// ---------------------------------------------------------------------------
extern "C" void kernel_launch(void* const* d_in, const int* in_sizes, int n_in,
                              void* d_out, int out_size, void* d_ws,
                              size_t ws_size, hipStream_t stream) {
  const float* hidden = (const float*)d_in[0];
  const float* gate_w = (const float*)d_in[1];
  const float* bias = (const float*)d_in[2];
  float* out = (float*)d_out;
  float* part = (float*)d_ws;

  const int nrows = in_sizes[0] / DD;  // 16384

  const size_t per = (size_t)nrows * EE * sizeof(float);  // 4 MiB
  int ksplit = (ws_size >= 4 * per) ? 4 : ((ws_size >= 2 * per) ? 2 : 1);

  dim3 block(256);
  dim3 grid(nrows / 64, ksplit);
  if (ksplit == 4)
    gemm_partial<4><<<grid, block, 0, stream>>>(hidden, gate_w, part, nrows);
  else if (ksplit == 2)
    gemm_partial<2><<<grid, block, 0, stream>>>(hidden, gate_w, part, nrows);
  else
    gemm_partial<1><<<grid, block, 0, stream>>>(hidden, gate_w, part, nrows);

  topk_kernel<<<dim3(nrows / 4), dim3(256), 0, stream>>>(part, bias, out,
                                                         nrows, ksplit);
}